// Round 1
// baseline (299.734 us; speedup 1.0000x reference)
//
#include <hip/hip_runtime.h>
#include <hip/hip_bf16.h>

typedef __bf16 bf16x8 __attribute__((ext_vector_type(8)));
typedef float f32x4 __attribute__((ext_vector_type(4)));

__device__ __forceinline__ unsigned short f2b(float f) {
    union { float f; unsigned int u; } v; v.f = f;
    unsigned int r = (v.u + 0x7FFFu + ((v.u >> 16) & 1u)) >> 16;
    return (unsigned short)r;
}

__device__ __forceinline__ void gload_lds16(const void* g, void* l) {
    __builtin_amdgcn_global_load_lds((__attribute__((address_space(1))) void*)g,
                                     (__attribute__((address_space(3))) void*)l,
                                     16, 0, 0);
}

// ---------------- converts ----------------

__global__ __launch_bounds__(256) void cvt_x_kernel(const float* __restrict__ in,
                                                    unsigned short* __restrict__ out) {
    int i = (blockIdx.x * 256 + threadIdx.x) * 4;
    float4 f = *(const float4*)(in + i);
    ushort4 u;
    u.x = f2b(f.x); u.y = f2b(f.y); u.z = f2b(f.z); u.w = f2b(f.w);
    *(ushort4*)(out + i) = u;
}

// in: R x C fp32, out: C x R bf16 (transposed)
__global__ __launch_bounds__(256) void transpose_cvt(const float* __restrict__ in,
                                                     unsigned short* __restrict__ out,
                                                     int R, int C) {
    __shared__ float t[32][33];
    int c0 = blockIdx.x * 32, r0 = blockIdx.y * 32;
    int tx = threadIdx.x, ty = threadIdx.y;
#pragma unroll
    for (int i = 0; i < 4; i++)
        t[ty + i * 8][tx] = in[(size_t)(r0 + ty + i * 8) * C + c0 + tx];
    __syncthreads();
#pragma unroll
    for (int i = 0; i < 4; i++)
        out[(size_t)(c0 + ty + i * 8) * R + r0 + tx] = f2b(t[tx][ty + i * 8]);
}

// ---------------- gates: sigmoid(x @ w_gates) -> [b*16+h][n] ----------------

__global__ __launch_bounds__(256) void gates_kernel(const float* __restrict__ x,
                                                    const float* __restrict__ wg,
                                                    float* __restrict__ gates) {
    int row = blockIdx.x;            // 0..4095  (b*2048+n)
    int b = row >> 11, n = row & 2047;
    int t = threadIdx.x;
    int h = t & 15, fi = t >> 4;     // fi 0..15
    const float* xr = x + (size_t)row * 1024;
    float s = 0.f;
    for (int f = fi; f < 1024; f += 16)
        s += xr[f] * wg[f * 16 + h];
    __shared__ float red[16][17];
    red[fi][h] = s;
    __syncthreads();
    if (t < 16) {
        float tot = 0.f;
#pragma unroll
        for (int i = 0; i < 16; i++) tot += red[i][t];
        float g = 1.f / (1.f + __expf(-tot));
        gates[((size_t)(b * 16 + t)) * 2048 + n] = g;
    }
}

// ---------------- GEMM: C = A[M][K] * Bt[N][K]^T, bf16 in, fp32 acc ----------------
// EPI 0: scatter to q (x0.125), k, v as [b][h][n][d] bf16
// EPI 1: fp32 out [M][N]

template <int EPI>
__global__ __launch_bounds__(256, 2)
void gemm_bt_kernel(const unsigned short* __restrict__ A,
                    const unsigned short* __restrict__ Bt,
                    int M, int N, int K,
                    unsigned short* __restrict__ outQ,
                    unsigned short* __restrict__ outK,
                    unsigned short* __restrict__ outV,
                    float* __restrict__ outF) {
    __shared__ unsigned short As[128 * 32];
    __shared__ unsigned short Bs[128 * 32];
    const int lane = threadIdx.x & 63;
    const int w = threadIdx.x >> 6;
    const int wr = w >> 1, wc = w & 1;
    const int tm = blockIdx.y * 128;
    const int tn = blockIdx.x * 128;

    f32x4 acc[4][4];
#pragma unroll
    for (int m = 0; m < 4; m++)
#pragma unroll
        for (int n = 0; n < 4; n++) acc[m][n] = (f32x4){0.f, 0.f, 0.f, 0.f};

    const int sRow = lane >> 2;          // 0..15 within 16-row chunk
    const int sCol = (lane & 3) * 8;     // element col within 32

    const unsigned short* aFragBase = As + (wr * 64 + (lane & 15)) * 32 + (lane >> 4) * 8;
    const unsigned short* bFragBase = Bs + (wc * 64 + (lane & 15)) * 32 + (lane >> 4) * 8;

    for (int k0 = 0; k0 < K; k0 += 32) {
#pragma unroll
        for (int i = 0; i < 2; i++) {
            int chunk = w * 2 + i;              // 0..7, wave-uniform
            int r = chunk * 16 + sRow;
            gload_lds16(A + (size_t)(tm + r) * K + k0 + sCol, (void*)(As + chunk * 512));
            gload_lds16(Bt + (size_t)(tn + r) * K + k0 + sCol, (void*)(Bs + chunk * 512));
        }
        __syncthreads();
        bf16x8 af[4], bg[4];
#pragma unroll
        for (int m = 0; m < 4; m++) af[m] = *(const bf16x8*)(aFragBase + m * 16 * 32);
#pragma unroll
        for (int n = 0; n < 4; n++) bg[n] = *(const bf16x8*)(bFragBase + n * 16 * 32);
#pragma unroll
        for (int m = 0; m < 4; m++)
#pragma unroll
            for (int n = 0; n < 4; n++)
                acc[m][n] = __builtin_amdgcn_mfma_f32_16x16x32_bf16(af[m], bg[n], acc[m][n], 0, 0, 0);
        __syncthreads();
    }

#pragma unroll
    for (int m = 0; m < 4; m++) {
        int row = tm + wr * 64 + m * 16 + (lane >> 4) * 4;
#pragma unroll
        for (int n = 0; n < 4; n++) {
            int col = tn + wc * 64 + n * 16 + (lane & 15);
#pragma unroll
            for (int r = 0; r < 4; r++) {
                float val = acc[m][n][r];
                int rr = row + r;
                if (EPI == 0) {
                    int which = col >> 10;
                    int h = (col >> 6) & 15;
                    int d = col & 63;
                    int b = rr >> 11;
                    int nn = rr & 2047;
                    size_t off = (((size_t)(b * 16 + h)) * 2048 + nn) * 64 + d;
                    if (which == 0)      outQ[off] = f2b(val * 0.125f);
                    else if (which == 1) outK[off] = f2b(val);
                    else                 outV[off] = f2b(val);
                } else {
                    outF[(size_t)rr * N + col] = val;
                }
            }
        }
    }
}

// ---------------- flash attention with softcap + causal + gate ----------------
// grid (32 qtiles, 32 bh), 256 threads = 4 waves x 16 q-rows

__global__ __launch_bounds__(256, 2)
void attn_kernel(const unsigned short* __restrict__ Q,
                 const unsigned short* __restrict__ Kg,
                 const unsigned short* __restrict__ Vg,
                 const float* __restrict__ Gates,
                 unsigned short* __restrict__ Out) {
    __shared__ unsigned short Vt[64][72];      // transposed V tile, padded
    __shared__ unsigned short Ps[4][16][72];   // per-wave P tile, padded

    const int lane = threadIdx.x & 63;
    const int w = threadIdx.x >> 6;
    const int bh = blockIdx.y;                 // b*16+h
    const int qt = 31 - blockIdx.x;            // heavy diagonal blocks first
    const int b = bh >> 4;
    const int h = bh & 15;

    const size_t headBase = (size_t)bh * 2048 * 64;

    const int qRow = qt * 64 + w * 16 + (lane & 15);
    const unsigned short* qp = Q + headBase + (size_t)qRow * 64 + (lane >> 4) * 8;
    bf16x8 qa0 = *(const bf16x8*)qp;
    bf16x8 qa1 = *(const bf16x8*)(qp + 32);

    float mrun[4], lrun[4];
    f32x4 o[4];
#pragma unroll
    for (int r = 0; r < 4; r++) { mrun[r] = -1e30f; lrun[r] = 0.f; }
#pragma unroll
    for (int n = 0; n < 4; n++) o[n] = (f32x4){0.f, 0.f, 0.f, 0.f};

    const int iRow0 = qt * 64 + w * 16 + (lane >> 4) * 4;   // + r

    const int vKv = threadIdx.x & 63;
    const int vD0 = (threadIdx.x >> 6) * 8;

    for (int jt = 0; jt <= qt; ++jt) {
        __syncthreads();   // previous tile's Vt reads done
        // stage V transposed: Vt[d][kv]
#pragma unroll
        for (int i = 0; i < 2; i++) {
            int d0 = vD0 + i * 32;
            bf16x8 tv = *(const bf16x8*)(Vg + headBase + (size_t)(jt * 64 + vKv) * 64 + d0);
#pragma unroll
            for (int j = 0; j < 8; j++) Vt[d0 + j][vKv] = ((const unsigned short*)&tv)[j];
        }

        // S = Q K^T via MFMA; K B-frags straight from global (L2-resident)
        f32x4 s[4];
#pragma unroll
        for (int n = 0; n < 4; n++) {
            const unsigned short* kp = Kg + headBase + (size_t)(jt * 64 + n * 16 + (lane & 15)) * 64 + (lane >> 4) * 8;
            bf16x8 kb0 = *(const bf16x8*)kp;
            bf16x8 kb1 = *(const bf16x8*)(kp + 32);
            f32x4 sv = (f32x4){0.f, 0.f, 0.f, 0.f};
            sv = __builtin_amdgcn_mfma_f32_16x16x32_bf16(qa0, kb0, sv, 0, 0, 0);
            sv = __builtin_amdgcn_mfma_f32_16x16x32_bf16(qa1, kb1, sv, 0, 0, 0);
            s[n] = sv;
        }

        // softcap + causal mask
        const bool diag = (jt == qt);
#pragma unroll
        for (int n = 0; n < 4; n++) {
            int jcol = jt * 64 + n * 16 + (lane & 15);
#pragma unroll
            for (int r = 0; r < 4; r++) {
                float x = s[n][r];
                float e = __expf(x * 0.04f);           // e^{2x/50}
                x = 50.f * (e - 1.f) / (e + 1.f);
                if (diag && jcol > iRow0 + r) x = -1e30f;
                s[n][r] = x;
            }
        }

        // row max across 64 cols (4 local + 16-lane xor reduce)
        float alpha[4], rsum[4];
#pragma unroll
        for (int r = 0; r < 4; r++) {
            float v0 = fmaxf(fmaxf(s[0][r], s[1][r]), fmaxf(s[2][r], s[3][r]));
            v0 = fmaxf(v0, __shfl_xor(v0, 1));
            v0 = fmaxf(v0, __shfl_xor(v0, 2));
            v0 = fmaxf(v0, __shfl_xor(v0, 4));
            v0 = fmaxf(v0, __shfl_xor(v0, 8));
            float mnew = fmaxf(mrun[r], v0);
            alpha[r] = __expf(mrun[r] - mnew);
            mrun[r] = mnew;
            rsum[r] = 0.f;
        }

        // P = exp(S - m), accumulate row sums
#pragma unroll
        for (int n = 0; n < 4; n++)
#pragma unroll
            for (int r = 0; r < 4; r++) {
                float p = __expf(s[n][r] - mrun[r]);
                s[n][r] = p;
                rsum[r] += p;
            }
#pragma unroll
        for (int r = 0; r < 4; r++) {
            float v0 = rsum[r];
            v0 += __shfl_xor(v0, 1);
            v0 += __shfl_xor(v0, 2);
            v0 += __shfl_xor(v0, 4);
            v0 += __shfl_xor(v0, 8);
            lrun[r] = lrun[r] * alpha[r] + v0;
        }
        // rescale O
#pragma unroll
        for (int n = 0; n < 4; n++)
#pragma unroll
            for (int r = 0; r < 4; r++) o[n][r] *= alpha[r];

        // P -> LDS (bf16), per-wave tile
#pragma unroll
        for (int n = 0; n < 4; n++)
#pragma unroll
            for (int r = 0; r < 4; r++)
                Ps[w][(lane >> 4) * 4 + r][n * 16 + (lane & 15)] = f2b(s[n][r]);

        __syncthreads();   // Vt staged + Ps written

        // O += P V
        bf16x8 pa0 = *(const bf16x8*)&Ps[w][lane & 15][(lane >> 4) * 8];
        bf16x8 pa1 = *(const bf16x8*)&Ps[w][lane & 15][32 + (lane >> 4) * 8];
#pragma unroll
        for (int n = 0; n < 4; n++) {
            bf16x8 vb0 = *(const bf16x8*)&Vt[n * 16 + (lane & 15)][(lane >> 4) * 8];
            bf16x8 vb1 = *(const bf16x8*)&Vt[n * 16 + (lane & 15)][32 + (lane >> 4) * 8];
            o[n] = __builtin_amdgcn_mfma_f32_16x16x32_bf16(pa0, vb0, o[n], 0, 0, 0);
            o[n] = __builtin_amdgcn_mfma_f32_16x16x32_bf16(pa1, vb1, o[n], 0, 0, 0);
        }
    }

    // epilogue: /l, *gate, write [b][n][h*64+d] bf16
#pragma unroll
    for (int r = 0; r < 4; r++) {
        int i = iRow0 + r;
        float g = Gates[(size_t)bh * 2048 + i];
        float inv = g / lrun[r];
#pragma unroll
        for (int n = 0; n < 4; n++)
            Out[((size_t)(b * 2048) + i) * 1024 + h * 64 + n * 16 + (lane & 15)] = f2b(o[n][r] * inv);
    }
}

// ---------------- launch ----------------

extern "C" void kernel_launch(void* const* d_in, const int* in_sizes, int n_in,
                              void* d_out, int out_size, void* d_ws, size_t ws_size,
                              hipStream_t stream) {
    const float* x       = (const float*)d_in[0];   // [2][2048][1024]
    const float* w_qkv   = (const float*)d_in[1];   // [1024][3072]
    const float* w_gates = (const float*)d_in[2];   // [1024][16]
    const float* w_out   = (const float*)d_in[3];   // [1024][1024]
    float* out = (float*)d_out;                     // [2][2048][1024]

    char* ws = (char*)d_ws;
    unsigned short* x_bf  = (unsigned short*)(ws);                      // 8 MB
    unsigned short* wqkvT = (unsigned short*)(ws + ((size_t)8  << 20)); // 6 MB
    unsigned short* woutT = (unsigned short*)(ws + ((size_t)14 << 20)); // 2 MB
    unsigned short* qB    = (unsigned short*)(ws + ((size_t)16 << 20)); // 8 MB
    unsigned short* kB    = (unsigned short*)(ws + ((size_t)24 << 20)); // 8 MB
    unsigned short* vB    = (unsigned short*)(ws + ((size_t)32 << 20)); // 8 MB
    float*          gates = (float*)(ws + ((size_t)40 << 20));          // 256 KB
    unsigned short* attnO = (unsigned short*)(ws + ((size_t)41 << 20)); // 8 MB

    cvt_x_kernel<<<dim3(4096), dim3(256), 0, stream>>>(x, x_bf);
    transpose_cvt<<<dim3(3072 / 32, 1024 / 32), dim3(32, 8), 0, stream>>>(w_qkv, wqkvT, 1024, 3072);
    transpose_cvt<<<dim3(1024 / 32, 1024 / 32), dim3(32, 8), 0, stream>>>(w_out, woutT, 1024, 1024);
    gates_kernel<<<dim3(4096), dim3(256), 0, stream>>>(x, w_gates, gates);

    gemm_bt_kernel<0><<<dim3(3072 / 128, 4096 / 128), dim3(256), 0, stream>>>(
        x_bf, wqkvT, 4096, 3072, 1024, qB, kB, vB, (float*)nullptr);

    attn_kernel<<<dim3(32, 32), dim3(256), 0, stream>>>(qB, kB, vB, gates, attnO);

    gemm_bt_kernel<1><<<dim3(1024 / 128, 4096 / 128), dim3(256), 0, stream>>>(
        attnO, woutT, 4096, 1024, 1024, nullptr, nullptr, nullptr, out);
}

// Round 2
// 292.766 us; speedup vs baseline: 1.0238x; 1.0238x over previous
//
#include <hip/hip_runtime.h>
#include <hip/hip_bf16.h>

typedef __bf16 bf16x8 __attribute__((ext_vector_type(8)));
typedef float f32x4 __attribute__((ext_vector_type(4)));

__device__ __forceinline__ unsigned short f2b(float f) {
    union { float f; unsigned int u; } v; v.f = f;
    unsigned int r = (v.u + 0x7FFFu + ((v.u >> 16) & 1u)) >> 16;
    return (unsigned short)r;
}

__device__ __forceinline__ void gload_lds16(const void* g, void* l) {
    __builtin_amdgcn_global_load_lds((__attribute__((address_space(1))) void*)g,
                                     (__attribute__((address_space(3))) void*)l,
                                     16, 0, 0);
}

// ---------------- converts ----------------

__global__ __launch_bounds__(256) void cvt_x_kernel(const float* __restrict__ in,
                                                    unsigned short* __restrict__ out) {
    int i = (blockIdx.x * 256 + threadIdx.x) * 4;
    float4 f = *(const float4*)(in + i);
    ushort4 u;
    u.x = f2b(f.x); u.y = f2b(f.y); u.z = f2b(f.z); u.w = f2b(f.w);
    *(ushort4*)(out + i) = u;
}

// in: R x C fp32, out: C x R bf16 (transposed)
__global__ __launch_bounds__(256) void transpose_cvt(const float* __restrict__ in,
                                                     unsigned short* __restrict__ out,
                                                     int R, int C) {
    __shared__ float t[32][33];
    int c0 = blockIdx.x * 32, r0 = blockIdx.y * 32;
    int tx = threadIdx.x, ty = threadIdx.y;
#pragma unroll
    for (int i = 0; i < 4; i++)
        t[ty + i * 8][tx] = in[(size_t)(r0 + ty + i * 8) * C + c0 + tx];
    __syncthreads();
#pragma unroll
    for (int i = 0; i < 4; i++)
        out[(size_t)(c0 + ty + i * 8) * R + r0 + tx] = f2b(t[tx][ty + i * 8]);
}

// V [bh][n][64] bf16 -> Vt [bh][64][n] bf16   (n tiles of 64)
__global__ __launch_bounds__(256) void vtrans_kernel(const unsigned short* __restrict__ V,
                                                     unsigned short* __restrict__ Vt) {
    __shared__ unsigned short t[64][72];
    int bh = blockIdx.y, n0 = blockIdx.x * 64;
    int r = threadIdx.x >> 2, cg = (threadIdx.x & 3) * 16;
    const unsigned short* src = V + ((size_t)bh * 2048 + n0 + r) * 64 + cg;
    *(bf16x8*)&t[r][cg]     = *(const bf16x8*)src;
    *(bf16x8*)&t[r][cg + 8] = *(const bf16x8*)(src + 8);
    __syncthreads();
    unsigned short tmp[16];
#pragma unroll
    for (int m = 0; m < 16; m++) tmp[m] = t[cg + m][r];
    unsigned short* dst = Vt + ((size_t)bh * 64 + r) * 2048 + n0 + cg;
    *(bf16x8*)dst       = *(const bf16x8*)tmp;
    *(bf16x8*)(dst + 8) = *(const bf16x8*)(tmp + 8);
}

// ---------------- gates: sigmoid(x @ w_gates) -> [b*16+h][n] ----------------

__global__ __launch_bounds__(256) void gates_kernel(const float* __restrict__ x,
                                                    const float* __restrict__ wg,
                                                    float* __restrict__ gates) {
    int row = blockIdx.x;            // 0..4095  (b*2048+n)
    int b = row >> 11, n = row & 2047;
    int t = threadIdx.x;
    int h = t & 15, fi = t >> 4;     // fi 0..15
    const float* xr = x + (size_t)row * 1024;
    float s = 0.f;
    for (int f = fi; f < 1024; f += 16)
        s += xr[f] * wg[f * 16 + h];
    __shared__ float red[16][17];
    red[fi][h] = s;
    __syncthreads();
    if (t < 16) {
        float tot = 0.f;
#pragma unroll
        for (int i = 0; i < 16; i++) tot += red[i][t];
        float g = 1.f / (1.f + __expf(-tot));
        gates[((size_t)(b * 16 + t)) * 2048 + n] = g;
    }
}

// ---------------- GEMM: C = A[M][K] * Bt[N][K]^T, bf16 in, fp32 acc ----------------

template <int EPI>
__global__ __launch_bounds__(256, 2)
void gemm_bt_kernel(const unsigned short* __restrict__ A,
                    const unsigned short* __restrict__ Bt,
                    int M, int N, int K,
                    unsigned short* __restrict__ outQ,
                    unsigned short* __restrict__ outK,
                    unsigned short* __restrict__ outV,
                    float* __restrict__ outF) {
    __shared__ unsigned short As[128 * 32];
    __shared__ unsigned short Bs[128 * 32];
    const int lane = threadIdx.x & 63;
    const int w = threadIdx.x >> 6;
    const int wr = w >> 1, wc = w & 1;
    const int tm = blockIdx.y * 128;
    const int tn = blockIdx.x * 128;

    f32x4 acc[4][4];
#pragma unroll
    for (int m = 0; m < 4; m++)
#pragma unroll
        for (int n = 0; n < 4; n++) acc[m][n] = (f32x4){0.f, 0.f, 0.f, 0.f};

    const int sRow = lane >> 2;
    const int sCol = (lane & 3) * 8;

    const unsigned short* aFragBase = As + (wr * 64 + (lane & 15)) * 32 + (lane >> 4) * 8;
    const unsigned short* bFragBase = Bs + (wc * 64 + (lane & 15)) * 32 + (lane >> 4) * 8;

    for (int k0 = 0; k0 < K; k0 += 32) {
#pragma unroll
        for (int i = 0; i < 2; i++) {
            int chunk = w * 2 + i;
            int r = chunk * 16 + sRow;
            gload_lds16(A + (size_t)(tm + r) * K + k0 + sCol, (void*)(As + chunk * 512));
            gload_lds16(Bt + (size_t)(tn + r) * K + k0 + sCol, (void*)(Bs + chunk * 512));
        }
        __syncthreads();
        bf16x8 af[4], bg[4];
#pragma unroll
        for (int m = 0; m < 4; m++) af[m] = *(const bf16x8*)(aFragBase + m * 16 * 32);
#pragma unroll
        for (int n = 0; n < 4; n++) bg[n] = *(const bf16x8*)(bFragBase + n * 16 * 32);
#pragma unroll
        for (int m = 0; m < 4; m++)
#pragma unroll
            for (int n = 0; n < 4; n++)
                acc[m][n] = __builtin_amdgcn_mfma_f32_16x16x32_bf16(af[m], bg[n], acc[m][n], 0, 0, 0);
        __syncthreads();
    }

#pragma unroll
    for (int m = 0; m < 4; m++) {
        int row = tm + wr * 64 + m * 16 + (lane >> 4) * 4;
#pragma unroll
        for (int n = 0; n < 4; n++) {
            int col = tn + wc * 64 + n * 16 + (lane & 15);
#pragma unroll
            for (int r = 0; r < 4; r++) {
                float val = acc[m][n][r];
                int rr = row + r;
                if (EPI == 0) {
                    int which = col >> 10;
                    int h = (col >> 6) & 15;
                    int d = col & 63;
                    int b = rr >> 11;
                    int nn = rr & 2047;
                    size_t off = (((size_t)(b * 16 + h)) * 2048 + nn) * 64 + d;
                    if (which == 0)      outQ[off] = f2b(val * 0.125f);
                    else if (which == 1) outK[off] = f2b(val);
                    else                 outV[off] = f2b(val);
                } else {
                    outF[(size_t)rr * N + col] = val;
                }
            }
        }
    }
}

// ---------------- flash attention: softcap + causal + gate ----------------
// grid 1024 blocks, 256 threads = 4 waves x 16 q-rows; no cross-wave LDS, no barriers

__global__ __launch_bounds__(256)
void attn_kernel(const unsigned short* __restrict__ Q,
                 const unsigned short* __restrict__ Kg,
                 const unsigned short* __restrict__ Vt,
                 const float* __restrict__ Gates,
                 unsigned short* __restrict__ Out) {
    __shared__ unsigned short Ps[4][16][72];   // per-wave P tile (no cross-wave use)

    const int lane = threadIdx.x & 63;
    const int w = threadIdx.x >> 6;

    // XCD-chunked swizzle: each XCD gets 4 consecutive bh (2MB K+V in its L2)
    const int nid = (blockIdx.x & 7) * 128 + (blockIdx.x >> 3);
    const int qt = 31 - (nid & 31);            // heavy diagonal tiles first
    const int bh = nid >> 5;
    const int b = bh >> 4;
    const int h = bh & 15;

    const size_t headBase = (size_t)bh * 2048 * 64;
    const float LOG2E = 1.4426950408889634f;

    const int qRow = qt * 64 + w * 16 + (lane & 15);
    const unsigned short* qp = Q + headBase + (size_t)qRow * 64 + (lane >> 4) * 8;
    bf16x8 qa0 = *(const bf16x8*)qp;
    bf16x8 qa1 = *(const bf16x8*)(qp + 32);

    float mrun[4], lrun[4];                    // mrun in log2 domain (m * log2e)
    f32x4 o[4];
#pragma unroll
    for (int r = 0; r < 4; r++) { mrun[r] = -1e30f; lrun[r] = 0.f; }
#pragma unroll
    for (int n = 0; n < 4; n++) o[n] = (f32x4){0.f, 0.f, 0.f, 0.f};

    const int iRow0 = qt * 64 + w * 16 + (lane >> 4) * 4;

    // K fragment base: row j -> Kfr + j*64
    const unsigned short* Kfr = Kg + headBase + (size_t)(lane & 15) * 64 + (lane >> 4) * 8;
    // Vt fragment base: d-row (n*16 + lane&15), kv col offset (lane>>4)*8
    const unsigned short* Vfr = Vt + (size_t)bh * 131072 + (size_t)(lane & 15) * 2048 + (lane >> 4) * 8;

    bf16x8 kb[4][2], vb[4][2];
#pragma unroll
    for (int n = 0; n < 4; n++) {
        const unsigned short* kp = Kfr + (size_t)(n * 16) * 64;
        kb[n][0] = *(const bf16x8*)kp;
        kb[n][1] = *(const bf16x8*)(kp + 32);
    }

    for (int jt = 0; jt <= qt; ++jt) {
        // S = Q K^T (consumes kb)
        f32x4 s[4];
#pragma unroll
        for (int n = 0; n < 4; n++) {
            f32x4 sv = (f32x4){0.f, 0.f, 0.f, 0.f};
            sv = __builtin_amdgcn_mfma_f32_16x16x32_bf16(qa0, kb[n][0], sv, 0, 0, 0);
            sv = __builtin_amdgcn_mfma_f32_16x16x32_bf16(qa1, kb[n][1], sv, 0, 0, 0);
            s[n] = sv;
        }

        // prefetch next K tile (overwrite kb; latency hides under softmax)
        {
            int jn = (jt < qt) ? jt + 1 : qt;
#pragma unroll
            for (int n = 0; n < 4; n++) {
                const unsigned short* kp = Kfr + (size_t)(jn * 64 + n * 16) * 64;
                kb[n][0] = *(const bf16x8*)kp;
                kb[n][1] = *(const bf16x8*)(kp + 32);
            }
        }
        // issue V loads for this tile (consumed after softmax)
#pragma unroll
        for (int n = 0; n < 4; n++) {
            const unsigned short* vp = Vfr + (size_t)(n * 16) * 2048 + jt * 64;
            vb[n][0] = *(const bf16x8*)vp;
            vb[n][1] = *(const bf16x8*)(vp + 32);
        }

        // softcap: s' = 50 - 100/(exp2(x*2/50*log2e)+1); causal mask on diagonal tile
        const bool diag = (jt == qt);
#pragma unroll
        for (int n = 0; n < 4; n++) {
            int jcol = jt * 64 + n * 16 + (lane & 15);
#pragma unroll
            for (int r = 0; r < 4; r++) {
                float x = s[n][r];
                float t = __builtin_amdgcn_exp2f(x * 0.057707801635559964f);
                float sc = 50.f - 100.f * __builtin_amdgcn_rcpf(t + 1.f);
                if (diag && jcol > iRow0 + r) sc = -1e30f;
                s[n][r] = sc;
            }
        }

        // online softmax (log2 domain)
        float rsum[4], alpha[4];
#pragma unroll
        for (int r = 0; r < 4; r++) {
            float v0 = fmaxf(fmaxf(s[0][r], s[1][r]), fmaxf(s[2][r], s[3][r]));
            v0 = fmaxf(v0, __shfl_xor(v0, 1));
            v0 = fmaxf(v0, __shfl_xor(v0, 2));
            v0 = fmaxf(v0, __shfl_xor(v0, 4));
            v0 = fmaxf(v0, __shfl_xor(v0, 8));
            float mnew = fmaxf(mrun[r], v0 * LOG2E);
            alpha[r] = __builtin_amdgcn_exp2f(mrun[r] - mnew);
            mrun[r] = mnew;
            rsum[r] = 0.f;
        }

#pragma unroll
        for (int n = 0; n < 4; n++)
#pragma unroll
            for (int r = 0; r < 4; r++) {
                float p = __builtin_amdgcn_exp2f(__builtin_fmaf(s[n][r], LOG2E, -mrun[r]));
                s[n][r] = p;
                rsum[r] += p;
            }
#pragma unroll
        for (int r = 0; r < 4; r++) {
            float v0 = rsum[r];
            v0 += __shfl_xor(v0, 1);
            v0 += __shfl_xor(v0, 2);
            v0 += __shfl_xor(v0, 4);
            v0 += __shfl_xor(v0, 8);
            lrun[r] = lrun[r] * alpha[r] + v0;
        }
#pragma unroll
        for (int n = 0; n < 4; n++)
#pragma unroll
            for (int r = 0; r < 4; r++) o[n][r] *= alpha[r];

        // P -> per-wave LDS tile -> A-fragment (within-wave, no barrier)
#pragma unroll
        for (int n = 0; n < 4; n++)
#pragma unroll
            for (int r = 0; r < 4; r++)
                Ps[w][(lane >> 4) * 4 + r][n * 16 + (lane & 15)] = f2b(s[n][r]);

        bf16x8 pa0 = *(const bf16x8*)&Ps[w][lane & 15][(lane >> 4) * 8];
        bf16x8 pa1 = *(const bf16x8*)&Ps[w][lane & 15][32 + (lane >> 4) * 8];

        // O += P V  (consumes vb)
#pragma unroll
        for (int n = 0; n < 4; n++) {
            o[n] = __builtin_amdgcn_mfma_f32_16x16x32_bf16(pa0, vb[n][0], o[n], 0, 0, 0);
            o[n] = __builtin_amdgcn_mfma_f32_16x16x32_bf16(pa1, vb[n][1], o[n], 0, 0, 0);
        }
    }

    // epilogue: /l, *gate, write [b][n][h*64+d] bf16
#pragma unroll
    for (int r = 0; r < 4; r++) {
        int i = iRow0 + r;
        float g = Gates[(size_t)bh * 2048 + i];
        float inv = g / lrun[r];
#pragma unroll
        for (int n = 0; n < 4; n++)
            Out[((size_t)(b * 2048) + i) * 1024 + h * 64 + n * 16 + (lane & 15)] = f2b(o[n][r] * inv);
    }
}

// ---------------- launch ----------------

extern "C" void kernel_launch(void* const* d_in, const int* in_sizes, int n_in,
                              void* d_out, int out_size, void* d_ws, size_t ws_size,
                              hipStream_t stream) {
    const float* x       = (const float*)d_in[0];   // [2][2048][1024]
    const float* w_qkv   = (const float*)d_in[1];   // [1024][3072]
    const float* w_gates = (const float*)d_in[2];   // [1024][16]
    const float* w_out   = (const float*)d_in[3];   // [1024][1024]
    float* out = (float*)d_out;                     // [2][2048][1024]

    char* ws = (char*)d_ws;
    unsigned short* x_bf  = (unsigned short*)(ws);                      // 8 MB (reused as Vt later)
    unsigned short* wqkvT = (unsigned short*)(ws + ((size_t)8  << 20)); // 6 MB
    unsigned short* woutT = (unsigned short*)(ws + ((size_t)14 << 20)); // 2 MB
    unsigned short* qB    = (unsigned short*)(ws + ((size_t)16 << 20)); // 8 MB
    unsigned short* kB    = (unsigned short*)(ws + ((size_t)24 << 20)); // 8 MB
    unsigned short* vB    = (unsigned short*)(ws + ((size_t)32 << 20)); // 8 MB
    float*          gates = (float*)(ws + ((size_t)40 << 20));          // 256 KB
    unsigned short* attnO = (unsigned short*)(ws + ((size_t)41 << 20)); // 8 MB
    unsigned short* vT    = x_bf;                                       // reuse after gemm0

    cvt_x_kernel<<<dim3(4096), dim3(256), 0, stream>>>(x, x_bf);
    transpose_cvt<<<dim3(3072 / 32, 1024 / 32), dim3(32, 8), 0, stream>>>(w_qkv, wqkvT, 1024, 3072);
    transpose_cvt<<<dim3(1024 / 32, 1024 / 32), dim3(32, 8), 0, stream>>>(w_out, woutT, 1024, 1024);
    gates_kernel<<<dim3(4096), dim3(256), 0, stream>>>(x, w_gates, gates);

    gemm_bt_kernel<0><<<dim3(3072 / 128, 4096 / 128), dim3(256), 0, stream>>>(
        x_bf, wqkvT, 4096, 3072, 1024, qB, kB, vB, (float*)nullptr);

    vtrans_kernel<<<dim3(32, 32), dim3(256), 0, stream>>>(vB, vT);

    attn_kernel<<<dim3(1024), dim3(256), 0, stream>>>(qB, kB, vT, gates, attnO);

    gemm_bt_kernel<1><<<dim3(1024 / 128, 4096 / 128), dim3(256), 0, stream>>>(
        attnO, woutT, 4096, 1024, 1024, nullptr, nullptr, nullptr, out);
}

// Round 3
// 238.054 us; speedup vs baseline: 1.2591x; 1.2298x over previous
//
#include <hip/hip_runtime.h>
#include <hip/hip_bf16.h>

typedef __bf16 bf16x8 __attribute__((ext_vector_type(8)));
typedef float f32x4 __attribute__((ext_vector_type(4)));

__device__ __forceinline__ unsigned short f2b(float f) {
    union { float f; unsigned int u; } v; v.f = f;
    unsigned int r = (v.u + 0x7FFFu + ((v.u >> 16) & 1u)) >> 16;
    return (unsigned short)r;
}

__device__ __forceinline__ void gload_lds16(const void* g, void* l) {
    __builtin_amdgcn_global_load_lds((__attribute__((address_space(1))) void*)g,
                                     (__attribute__((address_space(3))) void*)l,
                                     16, 0, 0);
}

// ---------------- converts ----------------

__global__ __launch_bounds__(256) void cvt_x_kernel(const float* __restrict__ in,
                                                    unsigned short* __restrict__ out) {
    int i = (blockIdx.x * 256 + threadIdx.x) * 4;
    float4 f = *(const float4*)(in + i);
    ushort4 u;
    u.x = f2b(f.x); u.y = f2b(f.y); u.z = f2b(f.z); u.w = f2b(f.w);
    *(ushort4*)(out + i) = u;
}

// in: R x C fp32, out: C x R bf16 (transposed)
__global__ __launch_bounds__(256) void transpose_cvt(const float* __restrict__ in,
                                                     unsigned short* __restrict__ out,
                                                     int R, int C) {
    __shared__ float t[32][33];
    int c0 = blockIdx.x * 32, r0 = blockIdx.y * 32;
    int tx = threadIdx.x, ty = threadIdx.y;
#pragma unroll
    for (int i = 0; i < 4; i++)
        t[ty + i * 8][tx] = in[(size_t)(r0 + ty + i * 8) * C + c0 + tx];
    __syncthreads();
#pragma unroll
    for (int i = 0; i < 4; i++)
        out[(size_t)(c0 + ty + i * 8) * R + r0 + tx] = f2b(t[tx][ty + i * 8]);
}

// V [bh][n][64] bf16 -> Vt [bh][64][n] bf16   (n tiles of 64)
__global__ __launch_bounds__(256) void vtrans_kernel(const unsigned short* __restrict__ V,
                                                     unsigned short* __restrict__ Vt) {
    __shared__ unsigned short t[64][72];
    int bh = blockIdx.y, n0 = blockIdx.x * 64;
    int r = threadIdx.x >> 2, cg = (threadIdx.x & 3) * 16;
    const unsigned short* src = V + ((size_t)bh * 2048 + n0 + r) * 64 + cg;
    *(bf16x8*)&t[r][cg]     = *(const bf16x8*)src;
    *(bf16x8*)&t[r][cg + 8] = *(const bf16x8*)(src + 8);
    __syncthreads();
    unsigned short tmp[16];
#pragma unroll
    for (int m = 0; m < 16; m++) tmp[m] = t[cg + m][r];
    unsigned short* dst = Vt + ((size_t)bh * 64 + r) * 2048 + n0 + cg;
    *(bf16x8*)dst       = *(const bf16x8*)tmp;
    *(bf16x8*)(dst + 8) = *(const bf16x8*)(tmp + 8);
}

// ---------------- gates: sigmoid(x @ w_gates) -> [b*16+h][n] ----------------

__global__ __launch_bounds__(256) void gates_kernel(const float* __restrict__ x,
                                                    const float* __restrict__ wg,
                                                    float* __restrict__ gates) {
    int row = blockIdx.x;            // 0..4095  (b*2048+n)
    int b = row >> 11, n = row & 2047;
    int t = threadIdx.x;
    int h = t & 15, fi = t >> 4;     // fi 0..15
    const float* xr = x + (size_t)row * 1024;
    float s = 0.f;
    for (int f = fi; f < 1024; f += 16)
        s += xr[f] * wg[f * 16 + h];
    __shared__ float red[16][17];
    red[fi][h] = s;
    __syncthreads();
    if (t < 16) {
        float tot = 0.f;
#pragma unroll
        for (int i = 0; i < 16; i++) tot += red[i][t];
        float g = 1.f / (1.f + __expf(-tot));
        gates[((size_t)(b * 16 + t)) * 2048 + n] = g;
    }
}

// ---------------- GEMM: C = A[M][K] * Bt[N][K]^T, bf16 in, fp32 acc ----------------

template <int EPI>
__global__ __launch_bounds__(256, 2)
void gemm_bt_kernel(const unsigned short* __restrict__ A,
                    const unsigned short* __restrict__ Bt,
                    int M, int N, int K,
                    unsigned short* __restrict__ outQ,
                    unsigned short* __restrict__ outK,
                    unsigned short* __restrict__ outV,
                    float* __restrict__ outF) {
    __shared__ unsigned short As[128 * 32];
    __shared__ unsigned short Bs[128 * 32];
    const int lane = threadIdx.x & 63;
    const int w = threadIdx.x >> 6;
    const int wr = w >> 1, wc = w & 1;
    const int tm = blockIdx.y * 128;
    const int tn = blockIdx.x * 128;

    f32x4 acc[4][4];
#pragma unroll
    for (int m = 0; m < 4; m++)
#pragma unroll
        for (int n = 0; n < 4; n++) acc[m][n] = (f32x4){0.f, 0.f, 0.f, 0.f};

    const int sRow = lane >> 2;
    const int sCol = (lane & 3) * 8;

    const unsigned short* aFragBase = As + (wr * 64 + (lane & 15)) * 32 + (lane >> 4) * 8;
    const unsigned short* bFragBase = Bs + (wc * 64 + (lane & 15)) * 32 + (lane >> 4) * 8;

    for (int k0 = 0; k0 < K; k0 += 32) {
#pragma unroll
        for (int i = 0; i < 2; i++) {
            int chunk = w * 2 + i;
            int r = chunk * 16 + sRow;
            gload_lds16(A + (size_t)(tm + r) * K + k0 + sCol, (void*)(As + chunk * 512));
            gload_lds16(Bt + (size_t)(tn + r) * K + k0 + sCol, (void*)(Bs + chunk * 512));
        }
        __syncthreads();
        bf16x8 af[4], bg[4];
#pragma unroll
        for (int m = 0; m < 4; m++) af[m] = *(const bf16x8*)(aFragBase + m * 16 * 32);
#pragma unroll
        for (int n = 0; n < 4; n++) bg[n] = *(const bf16x8*)(bFragBase + n * 16 * 32);
#pragma unroll
        for (int m = 0; m < 4; m++)
#pragma unroll
            for (int n = 0; n < 4; n++)
                acc[m][n] = __builtin_amdgcn_mfma_f32_16x16x32_bf16(af[m], bg[n], acc[m][n], 0, 0, 0);
        __syncthreads();
    }

#pragma unroll
    for (int m = 0; m < 4; m++) {
        int row = tm + wr * 64 + m * 16 + (lane >> 4) * 4;
#pragma unroll
        for (int n = 0; n < 4; n++) {
            int col = tn + wc * 64 + n * 16 + (lane & 15);
#pragma unroll
            for (int r = 0; r < 4; r++) {
                float val = acc[m][n][r];
                int rr = row + r;
                if (EPI == 0) {
                    int which = col >> 10;
                    int h = (col >> 6) & 15;
                    int d = col & 63;
                    int b = rr >> 11;
                    int nn = rr & 2047;
                    size_t off = (((size_t)(b * 16 + h)) * 2048 + nn) * 64 + d;
                    if (which == 0)      outQ[off] = f2b(val * 0.125f);
                    else if (which == 1) outK[off] = f2b(val);
                    else                 outV[off] = f2b(val);
                } else {
                    outF[(size_t)rr * N + col] = val;
                }
            }
        }
    }
}

// ---------------- flash attention: softcap + causal + gate ----------------
// 512 blocks = 32 bh x 16 pairs; block processes q-tiles {pair, 31-pair}
// => exactly 33 kv-tile iterations per block, perfectly balanced.
// 256 threads = 4 waves x 16 q-rows; no cross-wave LDS, no barriers.

__global__ __launch_bounds__(256)
void attn_kernel(const unsigned short* __restrict__ Q,
                 const unsigned short* __restrict__ Kg,
                 const unsigned short* __restrict__ Vt,
                 const float* __restrict__ Gates,
                 unsigned short* __restrict__ Out) {
    __shared__ unsigned short Ps[4][16][72];   // per-wave P tile (no cross-wave use)

    const int lane = threadIdx.x & 63;
    const int w = threadIdx.x >> 6;

    // XCD-chunked bijective swizzle: XCD i gets blocks [64i, 64i+64) = 4 heads
    const int wgid = (blockIdx.x & 7) * 64 + (blockIdx.x >> 3);
    const int bh = wgid >> 4;
    const int pair = wgid & 15;
    const int b = bh >> 4;
    const int h = bh & 15;

    const size_t headBase = (size_t)bh * 2048 * 64;
    const float LOG2E = 1.4426950408889634f;

    // lane-dependent, qt-independent bases
    const unsigned short* Kfr = Kg + headBase + (size_t)(lane & 15) * 64 + (lane >> 4) * 8;
    const unsigned short* Vfr = Vt + (size_t)bh * 131072 + (size_t)(lane & 15) * 2048 + (lane >> 4) * 8;

    for (int half = 0; half < 2; half++) {
        const int qt = half ? (31 - pair) : pair;

        const int qRow = qt * 64 + w * 16 + (lane & 15);
        const unsigned short* qp = Q + headBase + (size_t)qRow * 64 + (lane >> 4) * 8;
        bf16x8 qa0 = *(const bf16x8*)qp;
        bf16x8 qa1 = *(const bf16x8*)(qp + 32);

        float mrun[4], lrun[4];                // mrun in log2 domain
        f32x4 o[4];
#pragma unroll
        for (int r = 0; r < 4; r++) { mrun[r] = -1e30f; lrun[r] = 0.f; }
#pragma unroll
        for (int n = 0; n < 4; n++) o[n] = (f32x4){0.f, 0.f, 0.f, 0.f};

        const int iRow0 = qt * 64 + w * 16 + (lane >> 4) * 4;

        bf16x8 kb[4][2], vb[4][2];
#pragma unroll
        for (int n = 0; n < 4; n++) {
            const unsigned short* kp = Kfr + (size_t)(n * 16) * 64;
            kb[n][0] = *(const bf16x8*)kp;
            kb[n][1] = *(const bf16x8*)(kp + 32);
        }

        for (int jt = 0; jt <= qt; ++jt) {
            // S = Q K^T (consumes kb)
            f32x4 s[4];
#pragma unroll
            for (int n = 0; n < 4; n++) {
                f32x4 sv = (f32x4){0.f, 0.f, 0.f, 0.f};
                sv = __builtin_amdgcn_mfma_f32_16x16x32_bf16(qa0, kb[n][0], sv, 0, 0, 0);
                sv = __builtin_amdgcn_mfma_f32_16x16x32_bf16(qa1, kb[n][1], sv, 0, 0, 0);
                s[n] = sv;
            }

            // prefetch next K tile (latency hides under softmax)
            {
                int jn = (jt < qt) ? jt + 1 : 0;
#pragma unroll
                for (int n = 0; n < 4; n++) {
                    const unsigned short* kp = Kfr + (size_t)(jn * 64 + n * 16) * 64;
                    kb[n][0] = *(const bf16x8*)kp;
                    kb[n][1] = *(const bf16x8*)(kp + 32);
                }
            }
            // issue V loads for this tile (consumed after softmax)
#pragma unroll
            for (int n = 0; n < 4; n++) {
                const unsigned short* vp = Vfr + (size_t)(n * 16) * 2048 + jt * 64;
                vb[n][0] = *(const bf16x8*)vp;
                vb[n][1] = *(const bf16x8*)(vp + 32);
            }

            // softcap: s' = 50 - 100/(exp2(x*2/50*log2e)+1); causal mask on diagonal
            const bool diag = (jt == qt);
#pragma unroll
            for (int n = 0; n < 4; n++) {
                int jcol = jt * 64 + n * 16 + (lane & 15);
#pragma unroll
                for (int r = 0; r < 4; r++) {
                    float x = s[n][r];
                    float t = __builtin_amdgcn_exp2f(x * 0.057707801635559964f);
                    float sc = 50.f - 100.f * __builtin_amdgcn_rcpf(t + 1.f);
                    if (diag && jcol > iRow0 + r) sc = -1e30f;
                    s[n][r] = sc;
                }
            }

            // online softmax (log2 domain)
            float rsum[4], alpha[4];
#pragma unroll
            for (int r = 0; r < 4; r++) {
                float v0 = fmaxf(fmaxf(s[0][r], s[1][r]), fmaxf(s[2][r], s[3][r]));
                v0 = fmaxf(v0, __shfl_xor(v0, 1));
                v0 = fmaxf(v0, __shfl_xor(v0, 2));
                v0 = fmaxf(v0, __shfl_xor(v0, 4));
                v0 = fmaxf(v0, __shfl_xor(v0, 8));
                float mnew = fmaxf(mrun[r], v0 * LOG2E);
                alpha[r] = __builtin_amdgcn_exp2f(mrun[r] - mnew);
                mrun[r] = mnew;
                rsum[r] = 0.f;
            }

#pragma unroll
            for (int n = 0; n < 4; n++)
#pragma unroll
                for (int r = 0; r < 4; r++) {
                    float p = __builtin_amdgcn_exp2f(__builtin_fmaf(s[n][r], LOG2E, -mrun[r]));
                    s[n][r] = p;
                    rsum[r] += p;
                }
#pragma unroll
            for (int r = 0; r < 4; r++) {
                float v0 = rsum[r];
                v0 += __shfl_xor(v0, 1);
                v0 += __shfl_xor(v0, 2);
                v0 += __shfl_xor(v0, 4);
                v0 += __shfl_xor(v0, 8);
                lrun[r] = lrun[r] * alpha[r] + v0;
            }
#pragma unroll
            for (int n = 0; n < 4; n++)
#pragma unroll
                for (int r = 0; r < 4; r++) o[n][r] *= alpha[r];

            // P -> per-wave LDS tile -> A-fragment (within-wave, no barrier)
#pragma unroll
            for (int n = 0; n < 4; n++)
#pragma unroll
                for (int r = 0; r < 4; r++)
                    Ps[w][(lane >> 4) * 4 + r][n * 16 + (lane & 15)] = f2b(s[n][r]);

            bf16x8 pa0 = *(const bf16x8*)&Ps[w][lane & 15][(lane >> 4) * 8];
            bf16x8 pa1 = *(const bf16x8*)&Ps[w][lane & 15][32 + (lane >> 4) * 8];

            // O += P V  (consumes vb)
#pragma unroll
            for (int n = 0; n < 4; n++) {
                o[n] = __builtin_amdgcn_mfma_f32_16x16x32_bf16(pa0, vb[n][0], o[n], 0, 0, 0);
                o[n] = __builtin_amdgcn_mfma_f32_16x16x32_bf16(pa1, vb[n][1], o[n], 0, 0, 0);
            }
        }

        // epilogue: /l, *gate, write [b][n][h*64+d] bf16
#pragma unroll
        for (int r = 0; r < 4; r++) {
            int i = iRow0 + r;
            float g = Gates[(size_t)bh * 2048 + i];
            float inv = g / lrun[r];
#pragma unroll
            for (int n = 0; n < 4; n++)
                Out[((size_t)(b * 2048) + i) * 1024 + h * 64 + n * 16 + (lane & 15)] = f2b(o[n][r] * inv);
        }
    }
}

// ---------------- launch ----------------

extern "C" void kernel_launch(void* const* d_in, const int* in_sizes, int n_in,
                              void* d_out, int out_size, void* d_ws, size_t ws_size,
                              hipStream_t stream) {
    const float* x       = (const float*)d_in[0];   // [2][2048][1024]
    const float* w_qkv   = (const float*)d_in[1];   // [1024][3072]
    const float* w_gates = (const float*)d_in[2];   // [1024][16]
    const float* w_out   = (const float*)d_in[3];   // [1024][1024]
    float* out = (float*)d_out;                     // [2][2048][1024]

    char* ws = (char*)d_ws;
    unsigned short* x_bf  = (unsigned short*)(ws);                      // 8 MB (reused as Vt later)
    unsigned short* wqkvT = (unsigned short*)(ws + ((size_t)8  << 20)); // 6 MB
    unsigned short* woutT = (unsigned short*)(ws + ((size_t)14 << 20)); // 2 MB
    unsigned short* qB    = (unsigned short*)(ws + ((size_t)16 << 20)); // 8 MB
    unsigned short* kB    = (unsigned short*)(ws + ((size_t)24 << 20)); // 8 MB
    unsigned short* vB    = (unsigned short*)(ws + ((size_t)32 << 20)); // 8 MB
    float*          gates = (float*)(ws + ((size_t)40 << 20));          // 256 KB
    unsigned short* attnO = (unsigned short*)(ws + ((size_t)41 << 20)); // 8 MB
    unsigned short* vT    = x_bf;                                       // reuse after gemm0

    cvt_x_kernel<<<dim3(4096), dim3(256), 0, stream>>>(x, x_bf);
    transpose_cvt<<<dim3(3072 / 32, 1024 / 32), dim3(32, 8), 0, stream>>>(w_qkv, wqkvT, 1024, 3072);
    transpose_cvt<<<dim3(1024 / 32, 1024 / 32), dim3(32, 8), 0, stream>>>(w_out, woutT, 1024, 1024);
    gates_kernel<<<dim3(4096), dim3(256), 0, stream>>>(x, w_gates, gates);

    gemm_bt_kernel<0><<<dim3(3072 / 128, 4096 / 128), dim3(256), 0, stream>>>(
        x_bf, wqkvT, 4096, 3072, 1024, qB, kB, vB, (float*)nullptr);

    vtrans_kernel<<<dim3(32, 32), dim3(256), 0, stream>>>(vB, vT);

    attn_kernel<<<dim3(512), dim3(256), 0, stream>>>(qB, kB, vT, gates, attnO);

    gemm_bt_kernel<1><<<dim3(1024 / 128, 4096 / 128), dim3(256), 0, stream>>>(
        attnO, woutT, 4096, 1024, 1024, nullptr, nullptr, nullptr, out);
}